// Round 1
// baseline (217.384 us; speedup 1.0000x reference)
//
#include <hip/hip_runtime.h>
#include <hip/hip_bf16.h>
#include <cstdint>
#include <cstddef>

#define NROWS 16384
#define DDIM  256

typedef __attribute__((ext_vector_type(8))) short bf16x8;
typedef __attribute__((ext_vector_type(4))) float f32x4;
typedef __attribute__((ext_vector_type(4))) unsigned short us4;
typedef __attribute__((ext_vector_type(4))) float fl4;

// exp(x/T) = exp2(x * log2(e)/T)
constexpr float SCALE_EXP2 = 20.609929155556627f; // log2(e)/0.07
constexpr float LN2F       = 0.69314718055994531f;
constexpr float INV_T      = 14.285714285714286f; // 1/0.07

__device__ inline unsigned short f2bf(float x) {
  unsigned u = __float_as_uint(x);
  u += 0x7FFFu + ((u >> 16) & 1u);   // round-to-nearest-even
  return (unsigned short)(u >> 16);
}
__device__ inline float bf2f(unsigned short h) {
  return __uint_as_float(((unsigned)h) << 16);
}

// ---------------- kernel 1: L2-normalize rows of q and k -> bf16; zero d_out
__global__ void norm_kernel(const float* __restrict__ q, const float* __restrict__ k,
                            unsigned short* __restrict__ qn, unsigned short* __restrict__ kn,
                            float* __restrict__ out)
{
  int wave = threadIdx.x >> 6, lane = threadIdx.x & 63;
  bool is_k = blockIdx.x >= (NROWS / 4);
  int blk = is_k ? (blockIdx.x - NROWS / 4) : blockIdx.x;
  int row = blk * 4 + wave;                       // one wave per row
  const float* src = (is_k ? k : q) + (size_t)row * DDIM;
  unsigned short* dst = (is_k ? kn : qn) + (size_t)row * DDIM;

  fl4 v = *(const fl4*)(src + lane * 4);
  float ss = v.x * v.x + v.y * v.y + v.z * v.z + v.w * v.w;
#pragma unroll
  for (int m = 1; m < 64; m <<= 1) ss += __shfl_xor(ss, m, 64);
  float scale = 1.0f / fmaxf(sqrtf(ss), 1e-12f);

  us4 o;
  o.x = f2bf(v.x * scale); o.y = f2bf(v.y * scale);
  o.z = f2bf(v.z * scale); o.w = f2bf(v.w * scale);
  *(us4*)(dst + lane * 4) = o;

  if (blockIdx.x == 0 && threadIdx.x == 0) out[0] = 0.0f;
}

// ---------------- kernel 2: row-wise sum of exp(qn . kn^T / T), partial per col-split
// grid 512: blockIdx = rb*8 + split. WG: 4 waves, 256 rows (64/wave), col range 2048.
__global__ __launch_bounds__(256, 2) void lse_kernel(
    const unsigned short* __restrict__ qn, const unsigned short* __restrict__ kn,
    float* __restrict__ partial)
{
  __shared__ __attribute__((aligned(16))) unsigned short Bs[64 * DDIM]; // 32 KB, XOR-swizzled 16B chunks

  const int tid  = threadIdx.x;
  const int wave = tid >> 6, lane = tid & 63;
  const int l15  = lane & 15, quad = lane >> 4;
  const int split = blockIdx.x & 7;
  const int rb    = blockIdx.x >> 3;
  const int wrow  = rb * 256 + wave * 64;   // this wave's first row
  const int col_base = split * 2048;

  // Preload A fragments: 4 row-subtiles x 8 K-steps (K=256), 128 VGPRs.
  // A layout (16x16x32): m = lane&15, k = quad*8 + j
  bf16x8 A[4][8];
#pragma unroll
  for (int s = 0; s < 4; ++s) {
    const unsigned short* ap = qn + (size_t)(wrow + s * 16 + l15) * DDIM + quad * 8;
#pragma unroll
    for (int kt = 0; kt < 8; ++kt)
      A[s][kt] = *(const bf16x8*)(ap + kt * 32);
  }

  float sums[4][4];
#pragma unroll
  for (int s = 0; s < 4; ++s)
#pragma unroll
    for (int r = 0; r < 4; ++r) sums[s][r] = 0.0f;

  for (int ct = 0; ct < 32; ++ct) {
    const unsigned short* kbase = kn + (size_t)(col_base + ct * 64) * DDIM;
    __syncthreads();  // previous tile's reads complete before overwrite
    // Stage 64 cols x 256 k (32 KB) as 2048 16B chunks; chunk (n, slot jj)
    // holds global chunk j = jj ^ (n&31)  -> breaks the 512B-stride bank conflict.
#pragma unroll
    for (int i = 0; i < 8; ++i) {
      int L = i * 256 + tid;
      int n = L >> 5, jj = L & 31;
      int j = jj ^ (n & 31);
      *((bf16x8*)Bs + L) = *(const bf16x8*)(kbase + n * DDIM + j * 8);
    }
    __syncthreads();

#pragma unroll
    for (int cs = 0; cs < 4; ++cs) {
      int n  = cs * 16 + l15;            // B col this lane provides
      int nb = n & 31;
      const unsigned short* brow = Bs + n * DDIM;
      f32x4 acc0 = {0.f, 0.f, 0.f, 0.f};
      f32x4 acc1 = {0.f, 0.f, 0.f, 0.f};
      f32x4 acc2 = {0.f, 0.f, 0.f, 0.f};
      f32x4 acc3 = {0.f, 0.f, 0.f, 0.f};
#pragma unroll
      for (int kt = 0; kt < 8; ++kt) {
        bf16x8 b = *(const bf16x8*)(brow + (((kt * 4 + quad) ^ nb) * 8));
        acc0 = __builtin_amdgcn_mfma_f32_16x16x32_bf16(A[0][kt], b, acc0, 0, 0, 0);
        acc1 = __builtin_amdgcn_mfma_f32_16x16x32_bf16(A[1][kt], b, acc1, 0, 0, 0);
        acc2 = __builtin_amdgcn_mfma_f32_16x16x32_bf16(A[2][kt], b, acc2, 0, 0, 0);
        acc3 = __builtin_amdgcn_mfma_f32_16x16x32_bf16(A[3][kt], b, acc3, 0, 0, 0);
      }
      // C/D layout: col = lane&15, row = quad*4 + r. Bounded logits -> no max needed.
#pragma unroll
      for (int r = 0; r < 4; ++r) {
        sums[0][r] += __builtin_amdgcn_exp2f(acc0[r] * SCALE_EXP2);
        sums[1][r] += __builtin_amdgcn_exp2f(acc1[r] * SCALE_EXP2);
        sums[2][r] += __builtin_amdgcn_exp2f(acc2[r] * SCALE_EXP2);
        sums[3][r] += __builtin_amdgcn_exp2f(acc3[r] * SCALE_EXP2);
      }
    }
  }

  // Row totals: reduce across the 16 lanes (bits 0..3) sharing each (quad, r) row.
#pragma unroll
  for (int s = 0; s < 4; ++s)
#pragma unroll
    for (int r = 0; r < 4; ++r) {
      float v = sums[s][r];
      v += __shfl_xor(v, 1, 64);
      v += __shfl_xor(v, 2, 64);
      v += __shfl_xor(v, 4, 64);
      v += __shfl_xor(v, 8, 64);
      sums[s][r] = v;
    }
  if (l15 == 0) {
#pragma unroll
    for (int s = 0; s < 4; ++s)
#pragma unroll
      for (int r = 0; r < 4; ++r)
        partial[split * NROWS + wrow + s * 16 + quad * 4 + r] = sums[s][r];
  }
}

// ---------------- kernel 3: diag_i = dot(qn_i, kn_i) / T   (one wave per row)
__global__ void diag_kernel(const unsigned short* __restrict__ qn,
                            const unsigned short* __restrict__ kn,
                            float* __restrict__ diag)
{
  int wave = threadIdx.x >> 6, lane = threadIdx.x & 63;
  int row = blockIdx.x * 4 + wave;
  const unsigned short* qr = qn + (size_t)row * DDIM + lane * 4;
  const unsigned short* kr = kn + (size_t)row * DDIM + lane * 4;
  us4 a = *(const us4*)qr, b = *(const us4*)kr;
  float s = bf2f(a.x) * bf2f(b.x) + bf2f(a.y) * bf2f(b.y)
          + bf2f(a.z) * bf2f(b.z) + bf2f(a.w) * bf2f(b.w);
#pragma unroll
  for (int m = 1; m < 64; m <<= 1) s += __shfl_xor(s, m, 64);
  if (lane == 0) diag[row] = s * INV_T;
}

// ---------------- kernel 4: out = mean(log(sum_p partial) - diag)
__global__ void final_kernel(const float* __restrict__ partial,
                             const float* __restrict__ diag,
                             float* __restrict__ out)
{
  int row = blockIdx.x * 256 + threadIdx.x;
  float t = 0.0f;
#pragma unroll
  for (int p = 0; p < 8; ++p) t += partial[p * NROWS + row];
  float c = __builtin_amdgcn_logf(t) * LN2F - diag[row];
#pragma unroll
  for (int m = 1; m < 64; m <<= 1) c += __shfl_xor(c, m, 64);
  __shared__ float red[4];
  int wave = threadIdx.x >> 6, lane = threadIdx.x & 63;
  if (lane == 0) red[wave] = c;
  __syncthreads();
  if (threadIdx.x == 0) {
    float s = red[0] + red[1] + red[2] + red[3];
    atomicAdd(out, s * (1.0f / NROWS));
  }
}

extern "C" void kernel_launch(void* const* d_in, const int* in_sizes, int n_in,
                              void* d_out, int out_size, void* d_ws, size_t ws_size,
                              hipStream_t stream)
{
  const float* q = (const float*)d_in[0];
  const float* k = (const float*)d_in[1];
  float* out = (float*)d_out;

  char* ws = (char*)d_ws;
  unsigned short* qn = (unsigned short*)ws;                          // 8 MB
  unsigned short* kn = (unsigned short*)(ws + (8u << 20));           // 8 MB
  float* partial     = (float*)(ws + (16u << 20));                   // 8*16384*4 = 512 KB
  float* diag        = (float*)(ws + (16u << 20) + (512u << 10));    // 64 KB

  norm_kernel <<<8192, 256, 0, stream>>>(q, k, qn, kn, out);
  lse_kernel  <<<512,  256, 0, stream>>>(qn, kn, partial);
  diag_kernel <<<4096, 256, 0, stream>>>(qn, kn, diag);
  final_kernel<<<64,   256, 0, stream>>>(partial, diag, out);
}